// Round 2
// baseline (289.254 us; speedup 1.0000x reference)
//
#include <hip/hip_runtime.h>
#include <hip/hip_bf16.h>
#include <math.h>

#define EMBED 256
#define NF 3
#define DD 64
#define BM 128
#define BN 128
#define BK 64              // fp8 K-elements per pipeline phase
#define NKT 4              // EMBED / BK
#define MOTIF_BLOCKS 2048

typedef unsigned short ushort_t;
typedef unsigned char uchar_t;
typedef float f32x4 __attribute__((ext_vector_type(4)));
typedef float f32x2 __attribute__((ext_vector_type(2)));

__device__ __forceinline__ void gl2lds16(const void* g, void* l) {
    __builtin_amdgcn_global_load_lds(
        (const __attribute__((address_space(1))) unsigned int*)g,
        (__attribute__((address_space(3))) unsigned int*)l, 16, 0, 0);
}

__device__ __forceinline__ uchar_t f2fp8(float f) {
    int p = __builtin_amdgcn_cvt_pk_fp8_f32(f, f, 0, false);  // e4m3 OCP on gfx950
    return (uchar_t)(p & 0xff);
}
template<bool HI>
__device__ __forceinline__ f32x2 pk2(unsigned int w) {
    return __builtin_amdgcn_cvt_pk_f32_fp8((int)w, HI);       // .x = low byte
}

// ---------------- Kernel 1: normalize + random_mapping + MLP hidden ---------
// k_mlp1 fused in: xi/ffs are already in LDS per node; producing H here kills
// one kernel launch and the 3.8MB p round-trip.
__global__ __launch_bounds__(256) void k_embed(
    const float* __restrict__ x,
    const float* __restrict__ feats,
    const float* __restrict__ feat_free,
    const float* __restrict__ ks,
    const float* __restrict__ Ws,
    const float* __restrict__ bias,
    const float* __restrict__ W_free,
    const float* __restrict__ b_free,
    const float* __restrict__ W1,     // [96][64]
    const float* __restrict__ b1,     // [64]
    uchar_t* __restrict__ xnf8,       // [Npad][256] fp8 (normalized x, PRE-SCALED by 5)
    uchar_t* __restrict__ x2nf8,      // [Npad][256] fp8 (normalized x2)
    uchar_t* __restrict__ H8,         // [4][3][N][64] fp8
    float* __restrict__ acc3,         // 3 floats + ticket to zero
    int N, int Npad)
{
    int tid  = threadIdx.x;
    int wave = tid >> 6;
    int t    = tid & 63;
    int gtid = blockIdx.x * 256 + tid;
    int stride = gridDim.x * 256;

    for (int i = gtid; i < 4; i += stride) acc3[i] = 0.f;   // [3] = ticket (int 0)
    {
        int pad = (Npad - N) * (EMBED/4);
        int* pa = (int*)(xnf8  + (size_t)N*EMBED);
        int* pb = (int*)(x2nf8 + (size_t)N*EMBED);
        for (int i = gtid; i < pad; i += stride) { pa[i] = 0; pb[i] = 0; }
    }

    __shared__ float Wl[128*65];      // rows: [i*32+c] for Ws, [96+c] for W_free
    __shared__ float xi_s[4][NF][32];
    __shared__ float ff_s[4][32];

    for (int e = tid; e < NF*DD*32; e += 256) {
        int i = e >> 11, rem = e & 2047, tr = rem >> 5, c = rem & 31;
        Wl[(i*32 + c)*65 + tr] = Ws[e];
    }
    for (int e = tid; e < DD*32; e += 256) {
        int tr = e >> 5, c = e & 31;
        Wl[(96 + c)*65 + tr] = W_free[e];
    }
    __syncthreads();                   // Wl ready; no barriers needed below

    // W1 column for this lane (hidden dim t), in registers like old k_mlp1
    float wcol[96];
    #pragma unroll
    for (int c = 0; c < 96; ++c) wcol[c] = W1[c*64 + t];
    float b1l = b1[t];

    float (*xi)[32] = xi_s[wave];
    float* ffs = ff_s[wave];
    int ngroups = (N + 3) >> 2;

    for (int grp = blockIdx.x; grp < ngroups; grp += gridDim.x) {
        int n = grp*4 + wave;
        if (n >= N) continue;          // wave-uniform

        float v[NF];
        float ffv = 0.f;
        if (t < 32) {
            #pragma unroll
            for (int i = 0; i < NF; ++i) v[i] = feats[((size_t)i*N + n)*32 + t];
            ffv = feat_free[(size_t)n*32 + t];
        } else {
            #pragma unroll
            for (int i = 0; i < NF; ++i) v[i] = 0.f;
        }

        float num[NF];
        #pragma unroll
        for (int i = 0; i < NF; ++i) {
            float s = v[i]*v[i];
            s += __shfl_xor(s, 1, 64);  s += __shfl_xor(s, 2, 64);
            s += __shfl_xor(s, 4, 64);  s += __shfl_xor(s, 8, 64);
            s += __shfl_xor(s, 16, 64);
            s = __shfl(s, 0, 64);
            float k = ks[i];
            float scale = 0.45f / (sqrtf(s) * sqrtf(fabsf(k)));
            float xv = v[i] * scale;
            if (t < 32) xi[i][t] = xv;             // wave-local LDS (lgkmcnt ordering)
            num[i] = 1.0f + k * (scale*scale*s);
        }
        if (t < 32) ffs[t] = ffv;

        float z[4];
        float zsq = 0.f;
        #pragma unroll
        for (int i = 0; i < NF; ++i) {
            float div = 0.f;
            #pragma unroll
            for (int c = 0; c < 32; ++c) {
                float d = xi[i][c] - Wl[(i*32 + c)*65 + t];
                div += d*d;
            }
            float dist = __logf(num[i] / (div + 1e-5f));
            float zz = __expf(15.5f * dist) * __cosf(dist + bias[i*DD + t]);
            z[i] = zz;
            zsq += zz*zz;
        }
        {
            float dot = 0.f;
            #pragma unroll
            for (int c = 0; c < 32; ++c) dot = fmaf(ffs[c], Wl[(96 + c)*65 + t], dot);
            float zz = __expf(15.5f * dot) * __cosf(dot + b_free[t]);
            z[3] = zz;
            zsq += zz*zz;
        }
        zsq += __shfl_xor(zsq, 1, 64);  zsq += __shfl_xor(zsq, 2, 64);
        zsq += __shfl_xor(zsq, 4, 64);  zsq += __shfl_xor(zsq, 8, 64);
        zsq += __shfl_xor(zsq, 16, 64); zsq += __shfl_xor(zsq, 32, 64);
        float iv2 = 1.0f / sqrtf(zsq);

        #pragma unroll
        for (int i = 0; i < NF; ++i) x2nf8[(size_t)n*EMBED + i*DD + t] = f2fp8(z[i]*iv2);
        x2nf8[(size_t)n*EMBED + 192 + t] = f2fp8(z[3]*iv2);

        float xv[4];
        float s1 = 0.f;
        #pragma unroll
        for (int q = 0; q < 4; ++q) { xv[q] = x[(size_t)n*EMBED + q*64 + t]; s1 += xv[q]*xv[q]; }
        s1 += __shfl_xor(s1, 1, 64);  s1 += __shfl_xor(s1, 2, 64);
        s1 += __shfl_xor(s1, 4, 64);  s1 += __shfl_xor(s1, 8, 64);
        s1 += __shfl_xor(s1, 16, 64); s1 += __shfl_xor(s1, 32, 64);
        float iv1 = 5.0f / sqrtf(s1);          // pre-scale by 5 (1/TEMP)
        #pragma unroll
        for (int q = 0; q < 4; ++q) xnf8[(size_t)n*EMBED + q*64 + t] = f2fp8(xv[q]*iv1);

        // fused MLP hidden: H[prod][s][n][t], same math/order as old k_mlp1
        #pragma unroll
        for (int pr = 0; pr < 4; ++pr) {
            #pragma unroll
            for (int s = 0; s < 3; ++s) {
                float h = (s == 2) ? b1l : 0.f;
                #pragma unroll
                for (int c = 0; c < 32; ++c) {
                    float f = (pr < 3) ? xi[pr][c] : ffs[c];
                    h = fmaf(f, wcol[s*32 + c], h);
                }
                H8[(((size_t)pr*3 + s)*N + n)*64 + t] = f2fp8(h);
            }
        }
    }
}

// ---------------- Kernel 2: FUSED motif + pipelined GEMM -------------------
// Sim path rebuilt as T3 "minimum 2-phase": BK=64, double-buffered in the
// same 32KB (keeps 5 blocks/CU), next-phase global_load_lds issued BEFORE
// current-phase MFMA, ONE barrier per phase. LDS chunk swizzle sc=c^(r&3):
// at 64B row stride, a wave's ds_read_b64 region covers all 32 banks at
// 2 lanes/bank (was 4-way, 6.39M conflict cycles).
__global__ __launch_bounds__(256, 5) void k_fused(
    const uchar_t* __restrict__ xn, const uchar_t* __restrict__ x2n,
    const uchar_t* __restrict__ H,        // [4][3][N][64] fp8
    const int* __restrict__ motif,        // [3][M]
    const int* __restrict__ neg_uv,       // [2][M]
    const float* __restrict__ W2,
    const float* __restrict__ b2,
    float* __restrict__ rowpart,          // [nb][Npad]  (pcol-indexed partials)
    float* __restrict__ colpart,          // [nb][Npad]  (prow-indexed partials)
    float* __restrict__ pos,
    float* __restrict__ partials,         // [MOTIF_BLOCKS]
    int N, int Npad, int nb, int M)
{
    __shared__ __align__(16) uchar_t smem[2*(BM*BK + BN*BK)];   // 32768B

    if (blockIdx.x < MOTIF_BLOCKS) {
        // ---------------- motif path (unchanged) ----------------
        float* wred = (float*)smem;
        int lane = threadIdx.x & 63;
        int sub  = lane >> 3;
        int ch   = (lane & 7) * 8;
        int caseId = blockIdx.x & 7;
        int rank   = (blockIdx.x >> 3) * 4 + (threadIdx.x >> 6);   // 0..1023
        int prod  = caseId >> 1;
        int isneg = caseId & 1;
        const uchar_t* Hu = H + ((size_t)prod*3 + 0)*N*64;
        const uchar_t* Hv = H + ((size_t)prod*3 + 1)*N*64;
        const uchar_t* Hw = H + ((size_t)prod*3 + 2)*N*64;
        const int* iu = isneg ? neg_uv       : motif;
        const int* iv = isneg ? (neg_uv + M) : (motif + M);
        const int* iw = motif + 2*M;

        float w2c[8];
        #pragma unroll
        for (int c = 0; c < 8; ++c) w2c[c] = W2[ch + c];
        float b2v = b2[0];

        float accl = 0.f;
        #pragma unroll 2
        for (int r0 = rank*8; r0 < M; r0 += 8192) {
            int r = r0 + sub;
            bool ok = (r < M);
            int rc = ok ? r : 0;
            int u = iu[rc], v = iv[rc], w = iw[rc];
            uint2 du = *(const uint2*)&Hu[(size_t)u*64 + ch];
            uint2 dv = *(const uint2*)&Hv[(size_t)v*64 + ch];
            uint2 dw = *(const uint2*)&Hw[(size_t)w*64 + ch];
            float pl = 0.f;
            {
                f32x2 s;
                s = pk2<false>(du.x) + pk2<false>(dv.x) + pk2<false>(dw.x);
                pl = fmaf(fmaxf(s.x,0.f), w2c[0], pl);  pl = fmaf(fmaxf(s.y,0.f), w2c[1], pl);
                s = pk2<true>(du.x) + pk2<true>(dv.x) + pk2<true>(dw.x);
                pl = fmaf(fmaxf(s.x,0.f), w2c[2], pl);  pl = fmaf(fmaxf(s.y,0.f), w2c[3], pl);
                s = pk2<false>(du.y) + pk2<false>(dv.y) + pk2<false>(dw.y);
                pl = fmaf(fmaxf(s.x,0.f), w2c[4], pl);  pl = fmaf(fmaxf(s.y,0.f), w2c[5], pl);
                s = pk2<true>(du.y) + pk2<true>(dv.y) + pk2<true>(dw.y);
                pl = fmaf(fmaxf(s.x,0.f), w2c[6], pl);  pl = fmaf(fmaxf(s.y,0.f), w2c[7], pl);
            }
            pl += __shfl_xor(pl, 1, 64);
            pl += __shfl_xor(pl, 2, 64);
            pl += __shfl_xor(pl, 4, 64);
            float logit = pl + b2v;
            float z = isneg ? -logit : logit;
            float sp = fmaxf(-z, 0.f) + __logf(1.f + __expf(-fabsf(z)));
            accl -= ok ? sp : 0.f;
        }
        #pragma unroll
        for (int m = 1; m < 64; m <<= 1) accl += __shfl_xor(accl, m, 64);

        if (lane == 0) wred[threadIdx.x >> 6] = accl;
        __syncthreads();
        if (threadIdx.x == 0)
            partials[blockIdx.x] = (wred[0] + wred[1] + wred[2] + wred[3]) * 0.125f;
        return;
    }

    // ---------------- sim path ----------------
    int tid  = threadIdx.x;
    int lane = tid & 63;
    int w    = tid >> 6;
    int wr   = w >> 1, wc = w & 1;
    int quad = lane >> 4, l15 = lane & 15;

    int pid = blockIdx.x - MOTIF_BLOCKS;
    // bijective XCD swizzle (m204): contiguous wg chunk per XCD -> per-XCD
    // working set ~2.9MB < 4MB L2 (was: every XCD streams everything)
    int nwg = nb * nb;
    int qq = nwg >> 3, rr = nwg & 7;
    int xcd = pid & 7, idx = pid >> 3;
    int wg = (xcd < rr ? xcd*(qq+1) : rr*(qq+1) + (xcd-rr)*qq) + idx;

    int per_group = 8 * nb;
    int group = wg / per_group;
    int rem = wg - group * per_group;
    int rowspan = min(8, nb - group * 8);
    int prow = group * 8 + rem % rowspan;
    int pcol = rem / rowspan;
    int row0 = prow * BM, col0 = pcol * BN;

    f32x4 acc[4][4];
    #pragma unroll
    for (int i = 0; i < 4; ++i)
        #pragma unroll
        for (int j = 0; j < 4; ++j) acc[i][j] = (f32x4){0.f,0.f,0.f,0.f};

    // prologue: stage phase 0 into buffer 0
    {
        uchar_t* A = smem;
        uchar_t* B = smem + BM*BK;
        #pragma unroll
        for (int i = 0; i < 2; ++i) {
            int slot = i*256 + tid;          // slot = r*4 + c, 512 slots per tile
            int r = slot >> 2, c = slot & 3;
            int sc = c ^ (r & 3);
            gl2lds16(xn  + (size_t)(row0 + r)*EMBED + sc*16, &A[slot*16]);
            gl2lds16(x2n + (size_t)(col0 + r)*EMBED + sc*16, &B[slot*16]);
        }
    }
    __syncthreads();                          // vmcnt(0) drain + barrier

    #pragma unroll
    for (int kt = 0; kt < NKT; ++kt) {
        // issue next-phase stage FIRST -> HBM/L2 latency hides under MFMA
        if (kt + 1 < NKT) {
            uchar_t* A = smem + ((kt+1) & 1) * (BM*BK + BN*BK);
            uchar_t* B = A + BM*BK;
            int k0 = (kt+1) * BK;
            #pragma unroll
            for (int i = 0; i < 2; ++i) {
                int slot = i*256 + tid;
                int r = slot >> 2, c = slot & 3;
                int sc = c ^ (r & 3);
                gl2lds16(xn  + (size_t)(row0 + r)*EMBED + k0 + sc*16, &A[slot*16]);
                gl2lds16(x2n + (size_t)(col0 + r)*EMBED + k0 + sc*16, &B[slot*16]);
            }
        }
        // compute current phase
        {
            const uchar_t* A = smem + (kt & 1) * (BM*BK + BN*BK);
            const uchar_t* B = A + BM*BK;
            #pragma unroll
            for (int s = 0; s < 2; ++s) {    // 2 k-steps of K=32
                long a[4], b[4];
                int cq = s*2 + (quad >> 1);
                int h8 = (quad & 1) * 8;
                #pragma unroll
                for (int ti = 0; ti < 4; ++ti) {
                    int ra = wr*64 + ti*16 + l15;
                    a[ti] = *(const long*)&A[ra*BK + ((cq ^ (ra & 3)) << 4) + h8];
                }
                #pragma unroll
                for (int tj = 0; tj < 4; ++tj) {
                    int rb = wc*64 + tj*16 + l15;
                    b[tj] = *(const long*)&B[rb*BK + ((cq ^ (rb & 3)) << 4) + h8];
                }
                #pragma unroll
                for (int ti = 0; ti < 4; ++ti)
                    #pragma unroll
                    for (int tj = 0; tj < 4; ++tj)
                        acc[ti][tj] = __builtin_amdgcn_mfma_f32_16x16x32_fp8_fp8(a[ti], b[tj], acc[ti][tj], 0, 0, 0);
            }
        }
        __syncthreads();       // drains next-phase loads; frees cur buf for kt+2
    }

    // alias epilogue reduce arrays into smem (dead after K-loop)
    float* rsum_s = (float*)smem;
    float* csum_s = rsum_s + BM;
    if (tid < BM) { rsum_s[tid] = 0.f; csum_s[tid] = 0.f; }
    __syncthreads();

    // epilogue: e = exp(acc) (operands pre-scaled by 5), diag, row/col partials
    #pragma unroll
    for (int ti = 0; ti < 4; ++ti) {
        #pragma unroll
        for (int tj = 0; tj < 4; ++tj) {
            #pragma unroll
            for (int r = 0; r < 4; ++r) {
                int gi = row0 + wr*64 + ti*16 + quad*4 + r;
                int gj = col0 + wc*64 + tj*16 + l15;
                float e = 0.f;
                if (gi < N && gj < N) {
                    e = __expf(acc[ti][tj][r]);
                    if (gi == gj) pos[gi] = e;
                }
                acc[ti][tj][r] = e;
            }
        }
    }
    #pragma unroll
    for (int ti = 0; ti < 4; ++ti) {
        #pragma unroll
        for (int r = 0; r < 4; ++r) {
            float rsv = acc[ti][0][r] + acc[ti][1][r] + acc[ti][2][r] + acc[ti][3][r];
            rsv += __shfl_xor(rsv, 1, 64);
            rsv += __shfl_xor(rsv, 2, 64);
            rsv += __shfl_xor(rsv, 4, 64);
            rsv += __shfl_xor(rsv, 8, 64);
            if (l15 == 0) atomicAdd(&rsum_s[wr*64 + ti*16 + quad*4 + r], rsv);
        }
    }
    #pragma unroll
    for (int tj = 0; tj < 4; ++tj) {
        float csv = 0.f;
        #pragma unroll
        for (int ti = 0; ti < 4; ++ti)
            #pragma unroll
            for (int r = 0; r < 4; ++r) csv += acc[ti][tj][r];
        csv += __shfl_xor(csv, 16, 64);
        csv += __shfl_xor(csv, 32, 64);
        if (lane < 16) atomicAdd(&csum_s[wc*64 + tj*16 + lane], csv);
    }
    __syncthreads();
    if (tid < BM) {
        // contention-free partial stores
        rowpart[(size_t)pcol*Npad + row0 + tid] = rsum_s[tid];
        colpart[(size_t)prow*Npad + col0 + tid] = csum_s[tid];
    }
}

// ---------------- Kernel 3: log-reduction + ticket finalize -----------------
__global__ __launch_bounds__(256) void k_final(
    const float* __restrict__ rowpart, const float* __restrict__ colpart,
    const float* __restrict__ pos, const float* __restrict__ partials,
    float* __restrict__ acc3, int* __restrict__ ticket,
    float* __restrict__ out, int N, int Npad, int nb, int nparts, int M)
{
    __shared__ float red1[256], red2[256], red3[256];
    int t = threadIdx.x;
    int g = blockIdx.x * 256 + t;
    int stride = gridDim.x * 256;
    float l1 = 0.f, l2 = 0.f, mo = 0.f;
    for (int i = g; i < N; i += stride) {
        float rs = 0.f, cs = 0.f;
        for (int p = 0; p < nb; ++p) {
            rs += rowpart[(size_t)p*Npad + i];    // coalesced across threads
            cs += colpart[(size_t)p*Npad + i];
        }
        float pv = pos[i];
        l1 += __logf((cs - pv) / pv);
        l2 += __logf((rs - pv) / pv);
    }
    for (int i = g; i < nparts; i += stride) mo += partials[i];
    red1[t] = l1; red2[t] = l2; red3[t] = mo; __syncthreads();
    for (int s = 128; s > 0; s >>= 1) {
        if (t < s) { red1[t] += red1[t+s]; red2[t] += red2[t+s]; red3[t] += red3[t+s]; }
        __syncthreads();
    }
    if (t == 0) {
        atomicAdd(&acc3[0], red1[0]);
        atomicAdd(&acc3[1], red2[0]);
        atomicAdd(&acc3[2], red3[0]);
        __threadfence();                          // adds visible before ticket
        int old = atomicAdd(ticket, 1);
        if (old == (int)gridDim.x - 1) {
            // last block: read via device-scope RMW (coherent), finalize
            float a0 = atomicAdd(&acc3[0], 0.f);
            float a1 = atomicAdd(&acc3[1], 0.f);
            float a2 = atomicAdd(&acc3[2], 0.f);
            float cl = 0.5f * (a0 + a1) / (float)N;
            out[0] = cl - a2 / (float)M;
        }
    }
}

extern "C" void kernel_launch(void* const* d_in, const int* in_sizes, int n_in,
                              void* d_out, int out_size, void* d_ws, size_t ws_size,
                              hipStream_t stream)
{
    const float* x         = (const float*)d_in[0];
    const float* feats     = (const float*)d_in[1];
    const float* feat_free = (const float*)d_in[2];
    const float* ks        = (const float*)d_in[3];
    const float* Ws        = (const float*)d_in[4];
    const float* bias      = (const float*)d_in[5];
    const float* W_free    = (const float*)d_in[6];
    const float* b_free    = (const float*)d_in[7];
    const float* W1        = (const float*)d_in[8];
    const float* b1        = (const float*)d_in[9];
    const float* W2        = (const float*)d_in[10];
    const float* b2        = (const float*)d_in[11];
    const int*   motif     = (const int*)d_in[12];
    const int*   neg_uv    = (const int*)d_in[13];
    int N = in_sizes[0] / EMBED;          // 10000
    int M = in_sizes[13] / 2;             // 50000
    int nb = (N + BM - 1) / BM;           // 79
    int Npad = nb * BM;                   // 10112

    uchar_t* xnf8  = (uchar_t*)d_ws;                       // Npad*256 fp8
    uchar_t* x2nf8 = xnf8 + (size_t)Npad*EMBED;            // Npad*256 fp8
    uchar_t* H8    = x2nf8 + (size_t)Npad*EMBED;           // 12*N*64 fp8
    float* posv   = (float*)(H8 + (size_t)12*N*64);        // N
    float* acc3   = posv + N;                              // 3 + ticket (zeroed in k_embed)
    int*   ticket = (int*)(acc3 + 3);
    float* partials = acc3 + 4;                            // MOTIF_BLOCKS
    float* rowpart  = partials + MOTIF_BLOCKS;             // nb*Npad
    float* colpart  = rowpart + (size_t)nb*Npad;           // nb*Npad

    k_embed<<<512, 256, 0, stream>>>(x, feats, feat_free, ks, Ws, bias,
                                     W_free, b_free, W1, b1,
                                     xnf8, x2nf8, H8, acc3, N, Npad);
    k_fused<<<MOTIF_BLOCKS + nb*nb, 256, 0, stream>>>(xnf8, x2nf8, H8, motif, neg_uv,
                                                      W2, b2, rowpart, colpart, posv,
                                                      partials, N, Npad, nb, M);
    k_final<<<64, 256, 0, stream>>>(rowpart, colpart, posv, partials, acc3, ticket,
                                    (float*)d_out, N, Npad, nb, MOTIF_BLOCKS, M);
}

// Round 3
// 232.294 us; speedup vs baseline: 1.2452x; 1.2452x over previous
//
#include <hip/hip_runtime.h>
#include <hip/hip_bf16.h>
#include <math.h>

#define EMBED 256
#define NF 3
#define DD 64
#define BM 128
#define BN 128
#define BK 64              // fp8 K-elements per pipeline phase
#define NKT 4              // EMBED / BK
#define MOTIF_BLOCKS 2048

typedef unsigned short ushort_t;
typedef unsigned char uchar_t;
typedef float f32x4 __attribute__((ext_vector_type(4)));
typedef float f32x2 __attribute__((ext_vector_type(2)));

__device__ __forceinline__ void gl2lds16(const void* g, void* l) {
    __builtin_amdgcn_global_load_lds(
        (const __attribute__((address_space(1))) unsigned int*)g,
        (__attribute__((address_space(3))) unsigned int*)l, 16, 0, 0);
}

__device__ __forceinline__ uchar_t f2fp8(float f) {
    int p = __builtin_amdgcn_cvt_pk_fp8_f32(f, f, 0, false);  // e4m3 OCP on gfx950
    return (uchar_t)(p & 0xff);
}
template<bool HI>
__device__ __forceinline__ f32x2 pk2(unsigned int w) {
    return __builtin_amdgcn_cvt_pk_f32_fp8((int)w, HI);       // .x = low byte
}

// ---------------- Kernel 1: normalize + random_mapping (grid-stride) --------
__global__ __launch_bounds__(256) void k_embed(
    const float* __restrict__ x,
    const float* __restrict__ feats,
    const float* __restrict__ feat_free,
    const float* __restrict__ ks,
    const float* __restrict__ Ws,
    const float* __restrict__ bias,
    const float* __restrict__ W_free,
    const float* __restrict__ b_free,
    float* __restrict__ p_out,        // [3][N][32]
    uchar_t* __restrict__ xnf8,       // [Npad][256] fp8 (normalized x, PRE-SCALED by 5)
    uchar_t* __restrict__ x2nf8,      // [Npad][256] fp8 (normalized x2)
    float* __restrict__ acc3,         // 3 floats + ticket to zero
    int N, int Npad)
{
    int tid  = threadIdx.x;
    int wave = tid >> 6;
    int t    = tid & 63;
    int gtid = blockIdx.x * 256 + tid;
    int stride = gridDim.x * 256;

    for (int i = gtid; i < 4; i += stride) acc3[i] = 0.f;   // [3] = ticket
    {
        int pad = (Npad - N) * (EMBED/4);
        int* pa = (int*)(xnf8  + (size_t)N*EMBED);
        int* pb = (int*)(x2nf8 + (size_t)N*EMBED);
        for (int i = gtid; i < pad; i += stride) { pa[i] = 0; pb[i] = 0; }
    }

    __shared__ float Wl[128*65];      // rows: [i*32+c] for Ws, [96+c] for W_free
    __shared__ float xi_s[4][NF][32];
    __shared__ float ff_s[4][32];

    for (int e = tid; e < NF*DD*32; e += 256) {
        int i = e >> 11, rem = e & 2047, tr = rem >> 5, c = rem & 31;
        Wl[(i*32 + c)*65 + tr] = Ws[e];
    }
    for (int e = tid; e < DD*32; e += 256) {
        int tr = e >> 5, c = e & 31;
        Wl[(96 + c)*65 + tr] = W_free[e];
    }
    __syncthreads();                   // Wl ready; no barriers needed below

    float (*xi)[32] = xi_s[wave];
    float* ffs = ff_s[wave];
    int ngroups = (N + 3) >> 2;

    for (int grp = blockIdx.x; grp < ngroups; grp += gridDim.x) {
        int n = grp*4 + wave;
        if (n >= N) continue;          // wave-uniform

        float v[NF];
        float ffv = 0.f;
        if (t < 32) {
            #pragma unroll
            for (int i = 0; i < NF; ++i) v[i] = feats[((size_t)i*N + n)*32 + t];
            ffv = feat_free[(size_t)n*32 + t];
        } else {
            #pragma unroll
            for (int i = 0; i < NF; ++i) v[i] = 0.f;
        }

        float num[NF];
        #pragma unroll
        for (int i = 0; i < NF; ++i) {
            float s = v[i]*v[i];
            s += __shfl_xor(s, 1, 64);  s += __shfl_xor(s, 2, 64);
            s += __shfl_xor(s, 4, 64);  s += __shfl_xor(s, 8, 64);
            s += __shfl_xor(s, 16, 64);
            s = __shfl(s, 0, 64);
            float k = ks[i];
            float scale = 0.45f / (sqrtf(s) * sqrtf(fabsf(k)));
            float xv = v[i] * scale;
            if (t < 32) {
                xi[i][t] = xv;                       // wave-local LDS (lgkmcnt ordering)
                p_out[((size_t)i*N + n)*32 + t] = xv;
            }
            num[i] = 1.0f + k * (scale*scale*s);
        }
        if (t < 32) ffs[t] = ffv;

        float z[4];
        float zsq = 0.f;
        #pragma unroll
        for (int i = 0; i < NF; ++i) {
            float div = 0.f;
            #pragma unroll
            for (int c = 0; c < 32; ++c) {
                float d = xi[i][c] - Wl[(i*32 + c)*65 + t];
                div += d*d;
            }
            float dist = __logf(num[i] / (div + 1e-5f));
            float zz = __expf(15.5f * dist) * __cosf(dist + bias[i*DD + t]);
            z[i] = zz;
            zsq += zz*zz;
        }
        {
            float dot = 0.f;
            #pragma unroll
            for (int c = 0; c < 32; ++c) dot = fmaf(ffs[c], Wl[(96 + c)*65 + t], dot);
            float zz = __expf(15.5f * dot) * __cosf(dot + b_free[t]);
            z[3] = zz;
            zsq += zz*zz;
        }
        zsq += __shfl_xor(zsq, 1, 64);  zsq += __shfl_xor(zsq, 2, 64);
        zsq += __shfl_xor(zsq, 4, 64);  zsq += __shfl_xor(zsq, 8, 64);
        zsq += __shfl_xor(zsq, 16, 64); zsq += __shfl_xor(zsq, 32, 64);
        float iv2 = 1.0f / sqrtf(zsq);

        #pragma unroll
        for (int i = 0; i < NF; ++i) x2nf8[(size_t)n*EMBED + i*DD + t] = f2fp8(z[i]*iv2);
        x2nf8[(size_t)n*EMBED + 192 + t] = f2fp8(z[3]*iv2);

        float xv[4];
        float s1 = 0.f;
        #pragma unroll
        for (int q = 0; q < 4; ++q) { xv[q] = x[(size_t)n*EMBED + q*64 + t]; s1 += xv[q]*xv[q]; }
        s1 += __shfl_xor(s1, 1, 64);  s1 += __shfl_xor(s1, 2, 64);
        s1 += __shfl_xor(s1, 4, 64);  s1 += __shfl_xor(s1, 8, 64);
        s1 += __shfl_xor(s1, 16, 64); s1 += __shfl_xor(s1, 32, 64);
        float iv1 = 5.0f / sqrtf(s1);          // pre-scale by 5 (1/TEMP)
        #pragma unroll
        for (int q = 0; q < 4; ++q) xnf8[(size_t)n*EMBED + q*64 + t] = f2fp8(xv[q]*iv1);
    }
}

// ---------------- Kernel 2: per-node MLP hidden partials -> fp8 H -----------
__global__ __launch_bounds__(256) void k_mlp1(
    const float* __restrict__ p,          // [3][N][32]
    const float* __restrict__ feat_free,  // [N][32]
    const float* __restrict__ W1,         // [96][64]
    const float* __restrict__ b1,         // [64]
    uchar_t* __restrict__ H,              // [4][3][N][64] fp8
    int N)
{
    int lane = threadIdx.x & 63;
    int gw = (blockIdx.x * blockDim.x + threadIdx.x) >> 6;
    int nwaves = (gridDim.x * blockDim.x) >> 6;

    float wcol[96];
    #pragma unroll
    for (int c = 0; c < 96; ++c) wcol[c] = W1[c*64 + lane];
    float b1l = b1[lane];

    int total = 4 * N;
    for (int unit = gw; unit < total; unit += nwaves) {
        int node = __builtin_amdgcn_readfirstlane(unit >> 2);
        int prod = __builtin_amdgcn_readfirstlane(unit & 3);
        const float* P = (prod < 3) ? (p + ((size_t)prod*N + node)*32)
                                    : (feat_free + (size_t)node*32);
        float fc[32];
        #pragma unroll
        for (int c = 0; c < 32; ++c) fc[c] = P[c];
        #pragma unroll
        for (int s = 0; s < 3; ++s) {
            float h = (s == 2) ? b1l : 0.f;
            #pragma unroll
            for (int c = 0; c < 32; ++c) h = fmaf(fc[c], wcol[s*32 + c], h);
            H[(((size_t)prod*3 + s)*N + node)*64 + lane] = f2fp8(h);
        }
    }
}

// ---------------- Kernel 3: FUSED motif + pipelined GEMM -------------------
// T4 counted-vmcnt pipeline: raw s_barrier + s_waitcnt vmcnt(4) so next-phase
// global_load_lds stays in flight across the barrier (no full drains in-loop).
// Swizzle FIXED: sc = c ^ ((r>>1)&3) -> per-quad 8 bank-pairs x 2 lanes
// (b64 floor); previous c^(r&3) collapsed to 4 bank-pairs x 4 lanes (19.2M
// conflict cycles). Epilogue: per-wave disjoint LDS slots, no atomics.
__global__ __launch_bounds__(256, 5) void k_fused(
    const uchar_t* __restrict__ xn, const uchar_t* __restrict__ x2n,
    const uchar_t* __restrict__ H,        // [4][3][N][64] fp8
    const int* __restrict__ motif,        // [3][M]
    const int* __restrict__ neg_uv,       // [2][M]
    const float* __restrict__ W2,
    const float* __restrict__ b2,
    float* __restrict__ rowpart,          // [nb][Npad]  (pcol-indexed partials)
    float* __restrict__ colpart,          // [nb][Npad]  (prow-indexed partials)
    float* __restrict__ pos,
    float* __restrict__ partials,         // [MOTIF_BLOCKS]
    int N, int Npad, int nb, int M)
{
    __shared__ __align__(16) uchar_t smem[2*(BM*BK + BN*BK)];   // 32768B

    if (blockIdx.x < MOTIF_BLOCKS) {
        // ---------------- motif path (unchanged) ----------------
        float* wred = (float*)smem;
        int lane = threadIdx.x & 63;
        int sub  = lane >> 3;
        int ch   = (lane & 7) * 8;
        int caseId = blockIdx.x & 7;
        int rank   = (blockIdx.x >> 3) * 4 + (threadIdx.x >> 6);   // 0..1023
        int prod  = caseId >> 1;
        int isneg = caseId & 1;
        const uchar_t* Hu = H + ((size_t)prod*3 + 0)*N*64;
        const uchar_t* Hv = H + ((size_t)prod*3 + 1)*N*64;
        const uchar_t* Hw = H + ((size_t)prod*3 + 2)*N*64;
        const int* iu = isneg ? neg_uv       : motif;
        const int* iv = isneg ? (neg_uv + M) : (motif + M);
        const int* iw = motif + 2*M;

        float w2c[8];
        #pragma unroll
        for (int c = 0; c < 8; ++c) w2c[c] = W2[ch + c];
        float b2v = b2[0];

        float accl = 0.f;
        #pragma unroll 2
        for (int r0 = rank*8; r0 < M; r0 += 8192) {
            int r = r0 + sub;
            bool ok = (r < M);
            int rc = ok ? r : 0;
            int u = iu[rc], v = iv[rc], w = iw[rc];
            uint2 du = *(const uint2*)&Hu[(size_t)u*64 + ch];
            uint2 dv = *(const uint2*)&Hv[(size_t)v*64 + ch];
            uint2 dw = *(const uint2*)&Hw[(size_t)w*64 + ch];
            float pl = 0.f;
            {
                f32x2 s;
                s = pk2<false>(du.x) + pk2<false>(dv.x) + pk2<false>(dw.x);
                pl = fmaf(fmaxf(s.x,0.f), w2c[0], pl);  pl = fmaf(fmaxf(s.y,0.f), w2c[1], pl);
                s = pk2<true>(du.x) + pk2<true>(dv.x) + pk2<true>(dw.x);
                pl = fmaf(fmaxf(s.x,0.f), w2c[2], pl);  pl = fmaf(fmaxf(s.y,0.f), w2c[3], pl);
                s = pk2<false>(du.y) + pk2<false>(dv.y) + pk2<false>(dw.y);
                pl = fmaf(fmaxf(s.x,0.f), w2c[4], pl);  pl = fmaf(fmaxf(s.y,0.f), w2c[5], pl);
                s = pk2<true>(du.y) + pk2<true>(dv.y) + pk2<true>(dw.y);
                pl = fmaf(fmaxf(s.x,0.f), w2c[6], pl);  pl = fmaf(fmaxf(s.y,0.f), w2c[7], pl);
            }
            pl += __shfl_xor(pl, 1, 64);
            pl += __shfl_xor(pl, 2, 64);
            pl += __shfl_xor(pl, 4, 64);
            float logit = pl + b2v;
            float z = isneg ? -logit : logit;
            float sp = fmaxf(-z, 0.f) + __logf(1.f + __expf(-fabsf(z)));
            accl -= ok ? sp : 0.f;
        }
        #pragma unroll
        for (int m = 1; m < 64; m <<= 1) accl += __shfl_xor(accl, m, 64);

        if (lane == 0) wred[threadIdx.x >> 6] = accl;
        __syncthreads();
        if (threadIdx.x == 0)
            partials[blockIdx.x] = (wred[0] + wred[1] + wred[2] + wred[3]) * 0.125f;
        return;
    }

    // ---------------- sim path ----------------
    int tid  = threadIdx.x;
    int lane = tid & 63;
    int w    = tid >> 6;
    int wr   = w >> 1, wc = w & 1;
    int quad = lane >> 4, l15 = lane & 15;

    int pid = blockIdx.x - MOTIF_BLOCKS;
    // bijective XCD swizzle (m204)
    int nwg = nb * nb;
    int qq = nwg >> 3, rr = nwg & 7;
    int xcd = pid & 7, idx = pid >> 3;
    int wg = (xcd < rr ? xcd*(qq+1) : rr*(qq+1) + (xcd-rr)*qq) + idx;

    int per_group = 8 * nb;
    int group = wg / per_group;
    int rem = wg - group * per_group;
    int rowspan = min(8, nb - group * 8);
    int prow = group * 8 + rem % rowspan;
    int pcol = rem / rowspan;
    int row0 = prow * BM, col0 = pcol * BN;

    f32x4 acc[4][4];
    #pragma unroll
    for (int i = 0; i < 4; ++i)
        #pragma unroll
        for (int j = 0; j < 4; ++j) acc[i][j] = (f32x4){0.f,0.f,0.f,0.f};

    auto stage = [&](int t) {
        uchar_t* A = smem + (t & 1) * (BM*BK + BN*BK);
        uchar_t* B = A + BM*BK;
        int k0 = t * BK;
        #pragma unroll
        for (int i = 0; i < 2; ++i) {
            int slot = i*256 + tid;          // slot = r*4 + c, 512 slots per tile
            int r = slot >> 2, c = slot & 3;
            int sc = c ^ ((r >> 1) & 3);
            gl2lds16(xn  + (size_t)(row0 + r)*EMBED + k0 + sc*16, &A[slot*16]);
            gl2lds16(x2n + (size_t)(col0 + r)*EMBED + k0 + sc*16, &B[slot*16]);
        }
    };

    stage(0);                                 // 4 loads/wave in flight
    stage(1);                                 // 8 in flight

    #pragma unroll
    for (int kt = 0; kt < NKT; ++kt) {
        // counted wait: stage(kt) complete, stage(kt+1) may stay in flight
        if (kt == NKT-1) asm volatile("s_waitcnt vmcnt(0)" ::: "memory");
        else             asm volatile("s_waitcnt vmcnt(4)" ::: "memory");
        __builtin_amdgcn_s_barrier();         // buf(kt&1) globally ready

        const uchar_t* A = smem + (kt & 1) * (BM*BK + BN*BK);
        const uchar_t* B = A + BM*BK;
        #pragma unroll
        for (int s = 0; s < 2; ++s) {        // 2 k-steps of K=32
            long a[4], b[4];
            int cq = s*2 + (quad >> 1);
            int h8 = (quad & 1) * 8;
            #pragma unroll
            for (int ti = 0; ti < 4; ++ti) {
                int ra = wr*64 + ti*16 + l15;
                a[ti] = *(const long*)&A[ra*BK + ((cq ^ ((ra >> 1) & 3)) << 4) + h8];
            }
            #pragma unroll
            for (int tj = 0; tj < 4; ++tj) {
                int rb = wc*64 + tj*16 + l15;
                b[tj] = *(const long*)&B[rb*BK + ((cq ^ ((rb >> 1) & 3)) << 4) + h8];
            }
            #pragma unroll
            for (int ti = 0; ti < 4; ++ti)
                #pragma unroll
                for (int tj = 0; tj < 4; ++tj)
                    acc[ti][tj] = __builtin_amdgcn_mfma_f32_16x16x32_fp8_fp8(a[ti], b[tj], acc[ti][tj], 0, 0, 0);
        }
        if (kt + 2 < NKT) {
            __builtin_amdgcn_s_barrier();     // all waves done reading buf(kt&1)
            stage(kt + 2);                    // overwrite it for phase kt+2
        }
    }
    __syncthreads();                          // full drain once, before reuse

    // epilogue: per-wave DISJOINT LDS slots (no atomics, no init pass)
    float* rsum_s = (float*)smem;             // [2][BM]  indexed by wc
    float* csum_s = rsum_s + 2*BM;            // [2][BM]  indexed by wr

    #pragma unroll
    for (int ti = 0; ti < 4; ++ti) {
        #pragma unroll
        for (int tj = 0; tj < 4; ++tj) {
            #pragma unroll
            for (int r = 0; r < 4; ++r) {
                int gi = row0 + wr*64 + ti*16 + quad*4 + r;
                int gj = col0 + wc*64 + tj*16 + l15;
                float e = 0.f;
                if (gi < N && gj < N) {
                    e = __expf(acc[ti][tj][r]);
                    if (gi == gj) pos[gi] = e;
                }
                acc[ti][tj][r] = e;
            }
        }
    }
    #pragma unroll
    for (int ti = 0; ti < 4; ++ti) {
        #pragma unroll
        for (int r = 0; r < 4; ++r) {
            float rsv = acc[ti][0][r] + acc[ti][1][r] + acc[ti][2][r] + acc[ti][3][r];
            rsv += __shfl_xor(rsv, 1, 64);
            rsv += __shfl_xor(rsv, 2, 64);
            rsv += __shfl_xor(rsv, 4, 64);
            rsv += __shfl_xor(rsv, 8, 64);
            if (l15 == 0) rsum_s[wc*BM + wr*64 + ti*16 + quad*4 + r] = rsv;
        }
    }
    #pragma unroll
    for (int tj = 0; tj < 4; ++tj) {
        float csv = 0.f;
        #pragma unroll
        for (int ti = 0; ti < 4; ++ti)
            #pragma unroll
            for (int r = 0; r < 4; ++r) csv += acc[ti][tj][r];
        csv += __shfl_xor(csv, 16, 64);
        csv += __shfl_xor(csv, 32, 64);
        if (lane < 16) csum_s[wr*BM + wc*64 + tj*16 + lane] = csv;
    }
    __syncthreads();
    if (tid < BM) {
        rowpart[(size_t)pcol*Npad + row0 + tid] = rsum_s[tid] + rsum_s[BM + tid];
        colpart[(size_t)prow*Npad + col0 + tid] = csum_s[tid] + csum_s[BM + tid];
    }
}

// ---------------- Kernel 4: log-reduction + ticket finalize -----------------
__global__ __launch_bounds__(256) void k_final(
    const float* __restrict__ rowpart, const float* __restrict__ colpart,
    const float* __restrict__ pos, const float* __restrict__ partials,
    float* __restrict__ acc3, int* __restrict__ ticket,
    float* __restrict__ out, int N, int Npad, int nb, int nparts, int M)
{
    __shared__ float red1[256], red2[256], red3[256];
    int t = threadIdx.x;
    int g = blockIdx.x * 256 + t;
    int stride = gridDim.x * 256;
    float l1 = 0.f, l2 = 0.f, mo = 0.f;
    for (int i = g; i < N; i += stride) {
        float rs = 0.f, cs = 0.f;
        for (int p = 0; p < nb; ++p) {
            rs += rowpart[(size_t)p*Npad + i];    // coalesced across threads
            cs += colpart[(size_t)p*Npad + i];
        }
        float pv = pos[i];
        l1 += __logf((cs - pv) / pv);
        l2 += __logf((rs - pv) / pv);
    }
    for (int i = g; i < nparts; i += stride) mo += partials[i];
    red1[t] = l1; red2[t] = l2; red3[t] = mo; __syncthreads();
    for (int s = 128; s > 0; s >>= 1) {
        if (t < s) { red1[t] += red1[t+s]; red2[t] += red2[t+s]; red3[t] += red3[t+s]; }
        __syncthreads();
    }
    if (t == 0) {
        atomicAdd(&acc3[0], red1[0]);
        atomicAdd(&acc3[1], red2[0]);
        atomicAdd(&acc3[2], red3[0]);
        __threadfence();                          // adds visible before ticket
        int old = atomicAdd(ticket, 1);
        if (old == (int)gridDim.x - 1) {
            float a0 = atomicAdd(&acc3[0], 0.f);
            float a1 = atomicAdd(&acc3[1], 0.f);
            float a2 = atomicAdd(&acc3[2], 0.f);
            float cl = 0.5f * (a0 + a1) / (float)N;
            out[0] = cl - a2 / (float)M;
        }
    }
}

extern "C" void kernel_launch(void* const* d_in, const int* in_sizes, int n_in,
                              void* d_out, int out_size, void* d_ws, size_t ws_size,
                              hipStream_t stream)
{
    const float* x         = (const float*)d_in[0];
    const float* feats     = (const float*)d_in[1];
    const float* feat_free = (const float*)d_in[2];
    const float* ks        = (const float*)d_in[3];
    const float* Ws        = (const float*)d_in[4];
    const float* bias      = (const float*)d_in[5];
    const float* W_free    = (const float*)d_in[6];
    const float* b_free    = (const float*)d_in[7];
    const float* W1        = (const float*)d_in[8];
    const float* b1        = (const float*)d_in[9];
    const float* W2        = (const float*)d_in[10];
    const float* b2        = (const float*)d_in[11];
    const int*   motif     = (const int*)d_in[12];
    const int*   neg_uv    = (const int*)d_in[13];
    int N = in_sizes[0] / EMBED;          // 10000
    int M = in_sizes[13] / 2;             // 50000
    int nb = (N + BM - 1) / BM;           // 79
    int Npad = nb * BM;                   // 10112

    uchar_t* xnf8  = (uchar_t*)d_ws;                       // Npad*256 fp8
    uchar_t* x2nf8 = xnf8 + (size_t)Npad*EMBED;            // Npad*256 fp8
    uchar_t* H8    = x2nf8 + (size_t)Npad*EMBED;           // 12*N*64 fp8
    float* p      = (float*)(H8 + (size_t)12*N*64);        // 3*N*32
    float* posv   = p + (size_t)3*N*32;                    // N
    float* acc3   = posv + N;                              // 3 + ticket
    int*   ticket = (int*)(acc3 + 3);
    float* partials = acc3 + 4;                            // MOTIF_BLOCKS
    float* rowpart  = partials + MOTIF_BLOCKS;             // nb*Npad
    float* colpart  = rowpart + (size_t)nb*Npad;           // nb*Npad

    k_embed<<<512, 256, 0, stream>>>(x, feats, feat_free, ks, Ws, bias,
                                     W_free, b_free, p, xnf8, x2nf8,
                                     acc3, N, Npad);
    k_mlp1<<<1024, 256, 0, stream>>>(p, feat_free, W1, b1, H8, N);
    k_fused<<<MOTIF_BLOCKS + nb*nb, 256, 0, stream>>>(xnf8, x2nf8, H8, motif, neg_uv,
                                                      W2, b2, rowpart, colpart, posv,
                                                      partials, N, Npad, nb, M);
    k_final<<<64, 256, 0, stream>>>(rowpart, colpart, posv, partials, acc3, ticket,
                                    (float*)d_out, N, Npad, nb, MOTIF_BLOCKS, M);
}

// Round 4
// 219.628 us; speedup vs baseline: 1.3170x; 1.0577x over previous
//
#include <hip/hip_runtime.h>
#include <hip/hip_bf16.h>
#include <math.h>

#define EMBED 256
#define NF 3
#define DD 64
#define BM 128
#define BN 128
#define BK 64              // fp8 K-elements per pipeline phase
#define NKT 4              // EMBED / BK
#define MOTIF_BLOCKS 2048

typedef unsigned short ushort_t;
typedef unsigned char uchar_t;
typedef float f32x4 __attribute__((ext_vector_type(4)));
typedef float f32x2 __attribute__((ext_vector_type(2)));

__device__ __forceinline__ void gl2lds16(const void* g, void* l) {
    __builtin_amdgcn_global_load_lds(
        (const __attribute__((address_space(1))) unsigned int*)g,
        (__attribute__((address_space(3))) unsigned int*)l, 16, 0, 0);
}

__device__ __forceinline__ uchar_t f2fp8(float f) {
    int p = __builtin_amdgcn_cvt_pk_fp8_f32(f, f, 0, false);  // e4m3 OCP on gfx950
    return (uchar_t)(p & 0xff);
}
template<bool HI>
__device__ __forceinline__ f32x2 pk2(unsigned int w) {
    return __builtin_amdgcn_cvt_pk_f32_fp8((int)w, HI);       // .x = low byte
}

// Sum over the 16 lanes of each contiguous 16-lane row, entirely on the VALU
// pipe (DPP), replacing 4 DS-pipe ds_swizzle per value. After 4 steps every
// lane holds its 16-group total.
__device__ __forceinline__ float dpp16_red_add(float x) {
    int v;
    v = __builtin_amdgcn_update_dpp(0, __float_as_int(x), 0xB1, 0xF, 0xF, true);  // quad_perm xor1
    x += __int_as_float(v);
    v = __builtin_amdgcn_update_dpp(0, __float_as_int(x), 0x4E, 0xF, 0xF, true);  // quad_perm xor2
    x += __int_as_float(v);
    v = __builtin_amdgcn_update_dpp(0, __float_as_int(x), 0x141, 0xF, 0xF, true); // row_half_mirror
    x += __int_as_float(v);
    v = __builtin_amdgcn_update_dpp(0, __float_as_int(x), 0x140, 0xF, 0xF, true); // row_mirror
    x += __int_as_float(v);
    return x;
}

// ---------------- Kernel 1: normalize + random_mapping (grid-stride) --------
__global__ __launch_bounds__(256) void k_embed(
    const float* __restrict__ x,
    const float* __restrict__ feats,
    const float* __restrict__ feat_free,
    const float* __restrict__ ks,
    const float* __restrict__ Ws,
    const float* __restrict__ bias,
    const float* __restrict__ W_free,
    const float* __restrict__ b_free,
    float* __restrict__ p_out,        // [3][N][32]
    uchar_t* __restrict__ xnf8,       // [Npad][256] fp8 (normalized x, PRE-SCALED by 5)
    uchar_t* __restrict__ x2nf8,      // [Npad][256] fp8 (normalized x2)
    float* __restrict__ acc3,         // 3 floats + ticket to zero
    int N, int Npad)
{
    int tid  = threadIdx.x;
    int wave = tid >> 6;
    int t    = tid & 63;
    int gtid = blockIdx.x * 256 + tid;
    int stride = gridDim.x * 256;

    for (int i = gtid; i < 4; i += stride) acc3[i] = 0.f;   // [3] = ticket
    {
        int pad = (Npad - N) * (EMBED/4);
        int* pa = (int*)(xnf8  + (size_t)N*EMBED);
        int* pb = (int*)(x2nf8 + (size_t)N*EMBED);
        for (int i = gtid; i < pad; i += stride) { pa[i] = 0; pb[i] = 0; }
    }

    __shared__ float Wl[128*65];      // rows: [i*32+c] for Ws, [96+c] for W_free
    __shared__ float xi_s[4][NF][32];
    __shared__ float ff_s[4][32];

    for (int e = tid; e < NF*DD*32; e += 256) {
        int i = e >> 11, rem = e & 2047, tr = rem >> 5, c = rem & 31;
        Wl[(i*32 + c)*65 + tr] = Ws[e];
    }
    for (int e = tid; e < DD*32; e += 256) {
        int tr = e >> 5, c = e & 31;
        Wl[(96 + c)*65 + tr] = W_free[e];
    }
    __syncthreads();                   // Wl ready; no barriers needed below

    float (*xi)[32] = xi_s[wave];
    float* ffs = ff_s[wave];
    int ngroups = (N + 3) >> 2;

    for (int grp = blockIdx.x; grp < ngroups; grp += gridDim.x) {
        int n = grp*4 + wave;
        if (n >= N) continue;          // wave-uniform

        float v[NF];
        float ffv = 0.f;
        if (t < 32) {
            #pragma unroll
            for (int i = 0; i < NF; ++i) v[i] = feats[((size_t)i*N + n)*32 + t];
            ffv = feat_free[(size_t)n*32 + t];
        } else {
            #pragma unroll
            for (int i = 0; i < NF; ++i) v[i] = 0.f;
        }

        float num[NF];
        #pragma unroll
        for (int i = 0; i < NF; ++i) {
            float s = v[i]*v[i];
            s += __shfl_xor(s, 1, 64);  s += __shfl_xor(s, 2, 64);
            s += __shfl_xor(s, 4, 64);  s += __shfl_xor(s, 8, 64);
            s += __shfl_xor(s, 16, 64);
            s = __shfl(s, 0, 64);
            float k = ks[i];
            float scale = 0.45f / (sqrtf(s) * sqrtf(fabsf(k)));
            float xv = v[i] * scale;
            if (t < 32) {
                xi[i][t] = xv;                       // wave-local LDS (lgkmcnt ordering)
                p_out[((size_t)i*N + n)*32 + t] = xv;
            }
            num[i] = 1.0f + k * (scale*scale*s);
        }
        if (t < 32) ffs[t] = ffv;

        float z[4];
        float zsq = 0.f;
        #pragma unroll
        for (int i = 0; i < NF; ++i) {
            float div = 0.f;
            #pragma unroll
            for (int c = 0; c < 32; ++c) {
                float d = xi[i][c] - Wl[(i*32 + c)*65 + t];
                div += d*d;
            }
            float dist = __logf(num[i] / (div + 1e-5f));
            float zz = __expf(15.5f * dist) * __cosf(dist + bias[i*DD + t]);
            z[i] = zz;
            zsq += zz*zz;
        }
        {
            float dot = 0.f;
            #pragma unroll
            for (int c = 0; c < 32; ++c) dot = fmaf(ffs[c], Wl[(96 + c)*65 + t], dot);
            float zz = __expf(15.5f * dot) * __cosf(dot + b_free[t]);
            z[3] = zz;
            zsq += zz*zz;
        }
        zsq += __shfl_xor(zsq, 1, 64);  zsq += __shfl_xor(zsq, 2, 64);
        zsq += __shfl_xor(zsq, 4, 64);  zsq += __shfl_xor(zsq, 8, 64);
        zsq += __shfl_xor(zsq, 16, 64); zsq += __shfl_xor(zsq, 32, 64);
        float iv2 = 1.0f / sqrtf(zsq);

        #pragma unroll
        for (int i = 0; i < NF; ++i) x2nf8[(size_t)n*EMBED + i*DD + t] = f2fp8(z[i]*iv2);
        x2nf8[(size_t)n*EMBED + 192 + t] = f2fp8(z[3]*iv2);

        float xv[4];
        float s1 = 0.f;
        #pragma unroll
        for (int q = 0; q < 4; ++q) { xv[q] = x[(size_t)n*EMBED + q*64 + t]; s1 += xv[q]*xv[q]; }
        s1 += __shfl_xor(s1, 1, 64);  s1 += __shfl_xor(s1, 2, 64);
        s1 += __shfl_xor(s1, 4, 64);  s1 += __shfl_xor(s1, 8, 64);
        s1 += __shfl_xor(s1, 16, 64); s1 += __shfl_xor(s1, 32, 64);
        float iv1 = 5.0f / sqrtf(s1);          // pre-scale by 5 (1/TEMP)
        #pragma unroll
        for (int q = 0; q < 4; ++q) xnf8[(size_t)n*EMBED + q*64 + t] = f2fp8(xv[q]*iv1);
    }
}

// ---------------- Kernel 2: per-node MLP hidden partials -> fp8 H -----------
__global__ __launch_bounds__(256) void k_mlp1(
    const float* __restrict__ p,          // [3][N][32]
    const float* __restrict__ feat_free,  // [N][32]
    const float* __restrict__ W1,         // [96][64]
    const float* __restrict__ b1,         // [64]
    uchar_t* __restrict__ H,              // [4][3][N][64] fp8
    int N)
{
    int lane = threadIdx.x & 63;
    int gw = (blockIdx.x * blockDim.x + threadIdx.x) >> 6;
    int nwaves = (gridDim.x * blockDim.x) >> 6;

    float wcol[96];
    #pragma unroll
    for (int c = 0; c < 96; ++c) wcol[c] = W1[c*64 + lane];
    float b1l = b1[lane];

    int total = 4 * N;
    for (int unit = gw; unit < total; unit += nwaves) {
        int node = __builtin_amdgcn_readfirstlane(unit >> 2);
        int prod = __builtin_amdgcn_readfirstlane(unit & 3);
        const float* P = (prod < 3) ? (p + ((size_t)prod*N + node)*32)
                                    : (feat_free + (size_t)node*32);
        float fc[32];
        #pragma unroll
        for (int c = 0; c < 32; ++c) fc[c] = P[c];
        #pragma unroll
        for (int s = 0; s < 3; ++s) {
            float h = (s == 2) ? b1l : 0.f;
            #pragma unroll
            for (int c = 0; c < 32; ++c) h = fmaf(fc[c], wcol[s*32 + c], h);
            H[(((size_t)prod*3 + s)*N + node)*64 + lane] = f2fp8(h);
        }
    }
}

// ---------------- Kernel 3: FUSED motif + pipelined GEMM -------------------
// T4 counted-vmcnt pipeline (round 3, kept). Round 4: epilogue rebuilt as a
// single fused pass — no acc writeback, interior blocks (97.5%) skip all
// bounds checks, diag pos-store predicated to prow==pcol blocks via the
// closed-form lane condition, row-reduce on VALU via DPP (was 64 DS-pipe
// shuffles/thread). s_setprio(1) around MFMA cluster (T5).
__global__ __launch_bounds__(256, 4) void k_fused(
    const uchar_t* __restrict__ xn, const uchar_t* __restrict__ x2n,
    const uchar_t* __restrict__ H,        // [4][3][N][64] fp8
    const int* __restrict__ motif,        // [3][M]
    const int* __restrict__ neg_uv,       // [2][M]
    const float* __restrict__ W2,
    const float* __restrict__ b2,
    float* __restrict__ rowpart,          // [nb][Npad]  (pcol-indexed partials)
    float* __restrict__ colpart,          // [nb][Npad]  (prow-indexed partials)
    float* __restrict__ pos,
    float* __restrict__ partials,         // [MOTIF_BLOCKS]
    int N, int Npad, int nb, int M)
{
    __shared__ __align__(16) uchar_t smem[2*(BM*BK + BN*BK)];   // 32768B

    if (blockIdx.x < MOTIF_BLOCKS) {
        // ---------------- motif path (unchanged) ----------------
        float* wred = (float*)smem;
        int lane = threadIdx.x & 63;
        int sub  = lane >> 3;
        int ch   = (lane & 7) * 8;
        int caseId = blockIdx.x & 7;
        int rank   = (blockIdx.x >> 3) * 4 + (threadIdx.x >> 6);   // 0..1023
        int prod  = caseId >> 1;
        int isneg = caseId & 1;
        const uchar_t* Hu = H + ((size_t)prod*3 + 0)*N*64;
        const uchar_t* Hv = H + ((size_t)prod*3 + 1)*N*64;
        const uchar_t* Hw = H + ((size_t)prod*3 + 2)*N*64;
        const int* iu = isneg ? neg_uv       : motif;
        const int* iv = isneg ? (neg_uv + M) : (motif + M);
        const int* iw = motif + 2*M;

        float w2c[8];
        #pragma unroll
        for (int c = 0; c < 8; ++c) w2c[c] = W2[ch + c];
        float b2v = b2[0];

        float accl = 0.f;
        #pragma unroll 2
        for (int r0 = rank*8; r0 < M; r0 += 8192) {
            int r = r0 + sub;
            bool ok = (r < M);
            int rc = ok ? r : 0;
            int u = iu[rc], v = iv[rc], w = iw[rc];
            uint2 du = *(const uint2*)&Hu[(size_t)u*64 + ch];
            uint2 dv = *(const uint2*)&Hv[(size_t)v*64 + ch];
            uint2 dw = *(const uint2*)&Hw[(size_t)w*64 + ch];
            float pl = 0.f;
            {
                f32x2 s;
                s = pk2<false>(du.x) + pk2<false>(dv.x) + pk2<false>(dw.x);
                pl = fmaf(fmaxf(s.x,0.f), w2c[0], pl);  pl = fmaf(fmaxf(s.y,0.f), w2c[1], pl);
                s = pk2<true>(du.x) + pk2<true>(dv.x) + pk2<true>(dw.x);
                pl = fmaf(fmaxf(s.x,0.f), w2c[2], pl);  pl = fmaf(fmaxf(s.y,0.f), w2c[3], pl);
                s = pk2<false>(du.y) + pk2<false>(dv.y) + pk2<false>(dw.y);
                pl = fmaf(fmaxf(s.x,0.f), w2c[4], pl);  pl = fmaf(fmaxf(s.y,0.f), w2c[5], pl);
                s = pk2<true>(du.y) + pk2<true>(dv.y) + pk2<true>(dw.y);
                pl = fmaf(fmaxf(s.x,0.f), w2c[6], pl);  pl = fmaf(fmaxf(s.y,0.f), w2c[7], pl);
            }
            pl += __shfl_xor(pl, 1, 64);
            pl += __shfl_xor(pl, 2, 64);
            pl += __shfl_xor(pl, 4, 64);
            float logit = pl + b2v;
            float z = isneg ? -logit : logit;
            float sp = fmaxf(-z, 0.f) + __logf(1.f + __expf(-fabsf(z)));
            accl -= ok ? sp : 0.f;
        }
        #pragma unroll
        for (int m = 1; m < 64; m <<= 1) accl += __shfl_xor(accl, m, 64);

        if (lane == 0) wred[threadIdx.x >> 6] = accl;
        __syncthreads();
        if (threadIdx.x == 0)
            partials[blockIdx.x] = (wred[0] + wred[1] + wred[2] + wred[3]) * 0.125f;
        return;
    }

    // ---------------- sim path ----------------
    int tid  = threadIdx.x;
    int lane = tid & 63;
    int w    = tid >> 6;
    int wr   = w >> 1, wc = w & 1;
    int quad = lane >> 4, l15 = lane & 15;

    int pid = blockIdx.x - MOTIF_BLOCKS;
    // bijective XCD swizzle (m204)
    int nwg = nb * nb;
    int qq = nwg >> 3, rr = nwg & 7;
    int xcd = pid & 7, idx = pid >> 3;
    int wg = (xcd < rr ? xcd*(qq+1) : rr*(qq+1) + (xcd-rr)*qq) + idx;

    int per_group = 8 * nb;
    int group = wg / per_group;
    int rem = wg - group * per_group;
    int rowspan = min(8, nb - group * 8);
    int prow = group * 8 + rem % rowspan;
    int pcol = rem / rowspan;
    int row0 = prow * BM, col0 = pcol * BN;

    f32x4 acc[4][4];
    #pragma unroll
    for (int i = 0; i < 4; ++i)
        #pragma unroll
        for (int j = 0; j < 4; ++j) acc[i][j] = (f32x4){0.f,0.f,0.f,0.f};

    auto stage = [&](int t) {
        uchar_t* A = smem + (t & 1) * (BM*BK + BN*BK);
        uchar_t* B = A + BM*BK;
        int k0 = t * BK;
        #pragma unroll
        for (int i = 0; i < 2; ++i) {
            int slot = i*256 + tid;          // slot = r*4 + c, 512 slots per tile
            int r = slot >> 2, c = slot & 3;
            int sc = c ^ ((r >> 1) & 3);
            gl2lds16(xn  + (size_t)(row0 + r)*EMBED + k0 + sc*16, &A[slot*16]);
            gl2lds16(x2n + (size_t)(col0 + r)*EMBED + k0 + sc*16, &B[slot*16]);
        }
    };

    stage(0);                                 // 4 loads/wave in flight
    stage(1);                                 // 8 in flight

    #pragma unroll
    for (int kt = 0; kt < NKT; ++kt) {
        // counted wait: stage(kt) complete, stage(kt+1) may stay in flight
        if (kt == NKT-1) asm volatile("s_waitcnt vmcnt(0)" ::: "memory");
        else             asm volatile("s_waitcnt vmcnt(4)" ::: "memory");
        __builtin_amdgcn_s_barrier();         // buf(kt&1) globally ready

        const uchar_t* A = smem + (kt & 1) * (BM*BK + BN*BK);
        const uchar_t* B = A + BM*BK;
        #pragma unroll
        for (int s = 0; s < 2; ++s) {        // 2 k-steps of K=32
            long a[4], b[4];
            int cq = s*2 + (quad >> 1);
            int h8 = (quad & 1) * 8;
            #pragma unroll
            for (int ti = 0; ti < 4; ++ti) {
                int ra = wr*64 + ti*16 + l15;
                a[ti] = *(const long*)&A[ra*BK + ((cq ^ ((ra >> 1) & 3)) << 4) + h8];
            }
            #pragma unroll
            for (int tj = 0; tj < 4; ++tj) {
                int rb = wc*64 + tj*16 + l15;
                b[tj] = *(const long*)&B[rb*BK + ((cq ^ ((rb >> 1) & 3)) << 4) + h8];
            }
            __builtin_amdgcn_s_setprio(1);
            #pragma unroll
            for (int ti = 0; ti < 4; ++ti)
                #pragma unroll
                for (int tj = 0; tj < 4; ++tj)
                    acc[ti][tj] = __builtin_amdgcn_mfma_f32_16x16x32_fp8_fp8(a[ti], b[tj], acc[ti][tj], 0, 0, 0);
            __builtin_amdgcn_s_setprio(0);
        }
        if (kt + 2 < NKT) {
            __builtin_amdgcn_s_barrier();     // all waves done reading buf(kt&1)
            stage(kt + 2);                    // overwrite it for phase kt+2
        }
    }
    __syncthreads();                          // full drain once, before reuse

    // ---- fused single-pass epilogue ----
    float* rsum_s = (float*)smem;             // [2][BM]  indexed by wc
    float* csum_s = rsum_s + 2*BM;            // [2][BM]  indexed by wr

    bool edge = (prow == nb-1) || (pcol == nb-1);
    float csv[4] = {0.f, 0.f, 0.f, 0.f};

    if (!edge) {
        // interior: no bounds checks. gi==gj has solutions only when
        // wr==wc && ti==tj && l15==quad*4+r (|64Δwr|>63, |16Δti|>15 otherwise).
        bool diagb = (prow == pcol) && (wr == wc);
        #pragma unroll
        for (int ti = 0; ti < 4; ++ti) {
            #pragma unroll
            for (int r = 0; r < 4; ++r) {
                float rs = 0.f;
                #pragma unroll
                for (int tj = 0; tj < 4; ++tj) {
                    float e = __expf(acc[ti][tj][r]);
                    rs += e;
                    csv[tj] += e;
                    if (tj == ti && diagb && l15 == quad*4 + r)
                        pos[row0 + wr*64 + ti*16 + quad*4 + r] = e;
                }
                rs = dpp16_red_add(rs);
                if (l15 == 0) rsum_s[wc*BM + wr*64 + ti*16 + quad*4 + r] = rs;
            }
        }
    } else {
        #pragma unroll
        for (int ti = 0; ti < 4; ++ti) {
            #pragma unroll
            for (int r = 0; r < 4; ++r) {
                int gi = row0 + wr*64 + ti*16 + quad*4 + r;
                float rs = 0.f;
                #pragma unroll
                for (int tj = 0; tj < 4; ++tj) {
                    int gj = col0 + wc*64 + tj*16 + l15;
                    float e = 0.f;
                    if (gi < N && gj < N) {
                        e = __expf(acc[ti][tj][r]);
                        if (gi == gj) pos[gi] = e;
                    }
                    rs += e;
                    csv[tj] += e;
                }
                rs = dpp16_red_add(rs);
                if (l15 == 0) rsum_s[wc*BM + wr*64 + ti*16 + quad*4 + r] = rs;
            }
        }
    }
    #pragma unroll
    for (int tj = 0; tj < 4; ++tj) {
        float cs = csv[tj];
        cs += __shfl_xor(cs, 16, 64);
        cs += __shfl_xor(cs, 32, 64);
        if (lane < 16) csum_s[wr*BM + wc*64 + tj*16 + lane] = cs;
    }
    __syncthreads();
    if (tid < BM) {
        rowpart[(size_t)pcol*Npad + row0 + tid] = rsum_s[tid] + rsum_s[BM + tid];
        colpart[(size_t)prow*Npad + col0 + tid] = csum_s[tid] + csum_s[BM + tid];
    }
}

// ---------------- Kernel 4: log-reduction + ticket finalize -----------------
__global__ __launch_bounds__(256) void k_final(
    const float* __restrict__ rowpart, const float* __restrict__ colpart,
    const float* __restrict__ pos, const float* __restrict__ partials,
    float* __restrict__ acc3, int* __restrict__ ticket,
    float* __restrict__ out, int N, int Npad, int nb, int nparts, int M)
{
    __shared__ float red1[256], red2[256], red3[256];
    int t = threadIdx.x;
    int g = blockIdx.x * 256 + t;
    int stride = gridDim.x * 256;
    float l1 = 0.f, l2 = 0.f, mo = 0.f;
    for (int i = g; i < N; i += stride) {
        float rs = 0.f, cs = 0.f;
        for (int p = 0; p < nb; ++p) {
            rs += rowpart[(size_t)p*Npad + i];    // coalesced across threads
            cs += colpart[(size_t)p*Npad + i];
        }
        float pv = pos[i];
        l1 += __logf((cs - pv) / pv);
        l2 += __logf((rs - pv) / pv);
    }
    for (int i = g; i < nparts; i += stride) mo += partials[i];
    red1[t] = l1; red2[t] = l2; red3[t] = mo; __syncthreads();
    for (int s = 128; s > 0; s >>= 1) {
        if (t < s) { red1[t] += red1[t+s]; red2[t] += red2[t+s]; red3[t] += red3[t+s]; }
        __syncthreads();
    }
    if (t == 0) {
        atomicAdd(&acc3[0], red1[0]);
        atomicAdd(&acc3[1], red2[0]);
        atomicAdd(&acc3[2], red3[0]);
        __threadfence();                          // adds visible before ticket
        int old = atomicAdd(ticket, 1);
        if (old == (int)gridDim.x - 1) {
            float a0 = atomicAdd(&acc3[0], 0.f);
            float a1 = atomicAdd(&acc3[1], 0.f);
            float a2 = atomicAdd(&acc3[2], 0.f);
            float cl = 0.5f * (a0 + a1) / (float)N;
            out[0] = cl - a2 / (float)M;
        }
    }
}

extern "C" void kernel_launch(void* const* d_in, const int* in_sizes, int n_in,
                              void* d_out, int out_size, void* d_ws, size_t ws_size,
                              hipStream_t stream)
{
    const float* x         = (const float*)d_in[0];
    const float* feats     = (const float*)d_in[1];
    const float* feat_free = (const float*)d_in[2];
    const float* ks        = (const float*)d_in[3];
    const float* Ws        = (const float*)d_in[4];
    const float* bias      = (const float*)d_in[5];
    const float* W_free    = (const float*)d_in[6];
    const float* b_free    = (const float*)d_in[7];
    const float* W1        = (const float*)d_in[8];
    const float* b1        = (const float*)d_in[9];
    const float* W2        = (const float*)d_in[10];
    const float* b2        = (const float*)d_in[11];
    const int*   motif     = (const int*)d_in[12];
    const int*   neg_uv    = (const int*)d_in[13];
    int N = in_sizes[0] / EMBED;          // 10000
    int M = in_sizes[13] / 2;             // 50000
    int nb = (N + BM - 1) / BM;           // 79
    int Npad = nb * BM;                   // 10112

    uchar_t* xnf8  = (uchar_t*)d_ws;                       // Npad*256 fp8
    uchar_t* x2nf8 = xnf8 + (size_t)Npad*EMBED;            // Npad*256 fp8
    uchar_t* H8    = x2nf8 + (size_t)Npad*EMBED;           // 12*N*64 fp8
    float* p      = (float*)(H8 + (size_t)12*N*64);        // 3*N*32
    float* posv   = p + (size_t)3*N*32;                    // N
    float* acc3   = posv + N;                              // 3 + ticket
    int*   ticket = (int*)(acc3 + 3);
    float* partials = acc3 + 4;                            // MOTIF_BLOCKS
    float* rowpart  = partials + MOTIF_BLOCKS;             // nb*Npad
    float* colpart  = rowpart + (size_t)nb*Npad;           // nb*Npad

    k_embed<<<512, 256, 0, stream>>>(x, feats, feat_free, ks, Ws, bias,
                                     W_free, b_free, p, xnf8, x2nf8,
                                     acc3, N, Npad);
    k_mlp1<<<1024, 256, 0, stream>>>(p, feat_free, W1, b1, H8, N);
    k_fused<<<MOTIF_BLOCKS + nb*nb, 256, 0, stream>>>(xnf8, x2nf8, H8, motif, neg_uv,
                                                      W2, b2, rowpart, colpart, posv,
                                                      partials, N, Npad, nb, M);
    k_final<<<64, 256, 0, stream>>>(rowpart, colpart, posv, partials, acc3, ticket,
                                    (float*)d_out, N, Npad, nb, MOTIF_BLOCKS, M);
}